// Round 5
// baseline (51.753 us; speedup 1.0000x reference)
//
#include <hip/hip_runtime.h>
#include <math.h>

#define L_TOTAL 49152
#define NBLK 768
#define ROWS_PER_BLK 64   // L_TOTAL / NBLK
#define ROWS_PER_WAVE 16  // 4 waves per block

__device__ __forceinline__ float4 f4add(float4 a, float4 b) {
  return make_float4(a.x + b.x, a.y + b.y, a.z + b.z, a.w + b.w);
}

// Emulate np.float32 -> float16 (RNE, incl. subnormals) -> float32.
// Input x is positive and finite (x = 1/(l+1) <= 1).
__device__ __forceinline__ float fp16_roundtrip_pos(float x) {
  unsigned u = __float_as_uint(x);
  int e = (int)((u >> 23) & 0xffu) - 127;
  unsigned m = (u & 0x7fffffu) | 0x800000u;          // 24-bit mantissa
  int shift = (e >= -14) ? 13 : (13 + (-14 - e));    // extra shift for subnormals
  if (shift >= 25) return 0.0f;                      // underflow
  unsigned keep = m >> shift;
  unsigned rem = m & ((1u << shift) - 1u);
  unsigned halfbit = 1u << (shift - 1);
  if (rem > halfbit || (rem == halfbit && (keep & 1u))) keep++;
  return ldexpf((float)keep, e + shift - 23);
}

__device__ __forceinline__ void butterfly2(float4& a0, float4& a1) {
#pragma unroll
  for (int off = 32; off > 0; off >>= 1) {
    a0.x += __shfl_xor(a0.x, off); a0.y += __shfl_xor(a0.y, off);
    a0.z += __shfl_xor(a0.z, off); a0.w += __shfl_xor(a0.w, off);
    a1.x += __shfl_xor(a1.x, off); a1.y += __shfl_xor(a1.y, off);
    a1.z += __shfl_xor(a1.z, off); a1.w += __shfl_xor(a1.w, off);
  }
}

// Kernel A: g[b,l,c] = sum_f relu(s[b,l]*W_in[f]+pos_enc[l,f])*W_final[f,c]
// 64 rows/block (16 per wave), processed 2 rows at a time with both rows'
// loads in flight (latency hiding); 3 blocks/CU via __launch_bounds__(256,3).
__global__ __launch_bounds__(256, 3) void gpart_kernel(
    const int* __restrict__ ex, const float4* __restrict__ win4,
    const float4* __restrict__ pos4, const float4* __restrict__ wf4,
    float4* __restrict__ g4, float4* __restrict__ pp) {
  __shared__ float4 sg[2][ROWS_PER_BLK];
  __shared__ float4 wpart[2][4];

  const int lane = threadIdx.x & 63;
  const int wv = threadIdx.x >> 6;
  const int rowBase = blockIdx.x * ROWS_PER_BLK + wv * ROWS_PER_WAVE;

  // W_in / W_final fragments in registers, reused for all 16 rows.
  float4 win[4];
  float4 wf[4][4];
#pragma unroll
  for (int j = 0; j < 4; ++j) {
    const int fi = j * 64 + lane;  // float4 index into the 1024-long f axis
    win[j] = win4[fi];
#pragma unroll
    for (int k = 0; k < 4; ++k) wf[j][k] = wf4[fi * 4 + k];
  }

  float4 bp0 = make_float4(0.f, 0.f, 0.f, 0.f);
  float4 bp1 = make_float4(0.f, 0.f, 0.f, 0.f);

  for (int r = 0; r < ROWS_PER_WAVE; r += 2) {
    const int lA = rowBase + r;
    const int lB = lA + 1;
    // Issue all 8 pos_enc loads (2 rows x 4 float4) before any compute.
    float4 pA[4], pB[4];
#pragma unroll
    for (int j = 0; j < 4; ++j) pA[j] = pos4[(size_t)lA * 256 + j * 64 + lane];
#pragma unroll
    for (int j = 0; j < 4; ++j) pB[j] = pos4[(size_t)lB * 256 + j * 64 + lane];
    const float sA0 = (float)ex[lA] - 3.0f;          // ((e/4*2-1)*2-1) == e-3
    const float sA1 = (float)ex[L_TOTAL + lA] - 3.0f;
    const float sB0 = (float)ex[lB] - 3.0f;
    const float sB1 = (float)ex[L_TOTAL + lB] - 3.0f;

    float4 aA0 = make_float4(0.f, 0.f, 0.f, 0.f);
    float4 aA1 = make_float4(0.f, 0.f, 0.f, 0.f);
    float4 aB0 = make_float4(0.f, 0.f, 0.f, 0.f);
    float4 aB1 = make_float4(0.f, 0.f, 0.f, 0.f);
#pragma unroll
    for (int j = 0; j < 4; ++j) {
      const float pcA[4] = {pA[j].x, pA[j].y, pA[j].z, pA[j].w};
      const float pcB[4] = {pB[j].x, pB[j].y, pB[j].z, pB[j].w};
      const float wc[4] = {win[j].x, win[j].y, win[j].z, win[j].w};
#pragma unroll
      for (int k = 0; k < 4; ++k) {
        const float4 w = wf[j][k];
        const float tA0 = fmaxf(fmaf(sA0, wc[k], pcA[k]), 0.0f);
        const float tA1 = fmaxf(fmaf(sA1, wc[k], pcA[k]), 0.0f);
        const float tB0 = fmaxf(fmaf(sB0, wc[k], pcB[k]), 0.0f);
        const float tB1 = fmaxf(fmaf(sB1, wc[k], pcB[k]), 0.0f);
        aA0.x = fmaf(tA0, w.x, aA0.x); aA0.y = fmaf(tA0, w.y, aA0.y);
        aA0.z = fmaf(tA0, w.z, aA0.z); aA0.w = fmaf(tA0, w.w, aA0.w);
        aA1.x = fmaf(tA1, w.x, aA1.x); aA1.y = fmaf(tA1, w.y, aA1.y);
        aA1.z = fmaf(tA1, w.z, aA1.z); aA1.w = fmaf(tA1, w.w, aA1.w);
        aB0.x = fmaf(tB0, w.x, aB0.x); aB0.y = fmaf(tB0, w.y, aB0.y);
        aB0.z = fmaf(tB0, w.z, aB0.z); aB0.w = fmaf(tB0, w.w, aB0.w);
        aB1.x = fmaf(tB1, w.x, aB1.x); aB1.y = fmaf(tB1, w.y, aB1.y);
        aB1.z = fmaf(tB1, w.z, aB1.z); aB1.w = fmaf(tB1, w.w, aB1.w);
      }
    }
    // Two independent butterfly chains (rows A,B) interleave on the LDS pipe.
    butterfly2(aA0, aA1);
    butterfly2(aB0, aB1);
    bp0 = f4add(bp0, f4add(aA0, aB0));
    bp1 = f4add(bp1, f4add(aA1, aB1));
    if (lane == 0) {
      sg[0][wv * ROWS_PER_WAVE + r] = aA0;
      sg[1][wv * ROWS_PER_WAVE + r] = aA1;
      sg[0][wv * ROWS_PER_WAVE + r + 1] = aB0;
      sg[1][wv * ROWS_PER_WAVE + r + 1] = aB1;
    }
  }

  if (lane == 0) { wpart[0][wv] = bp0; wpart[1][wv] = bp1; }
  __syncthreads();

  // Coalesced dump of the 128 g rows + 2 partial sums.
  if (threadIdx.x < 2 * ROWS_PER_BLK) {
    const int bb = threadIdx.x / ROWS_PER_BLK;
    const int i = threadIdx.x - bb * ROWS_PER_BLK;
    g4[(size_t)bb * L_TOTAL + blockIdx.x * ROWS_PER_BLK + i] = sg[bb][i];
  }
  if (threadIdx.x < 2) {
    const int bb = threadIdx.x;
    pp[bb * NBLK + blockIdx.x] =
        f4add(f4add(wpart[bb][0], wpart[bb][1]),
              f4add(wpart[bb][2], wpart[bb][3]));
  }
}

// Kernel B: per block -- offset = sum of preceding blocks' partials (L2-hot),
// intra-block inclusive scan of 64 rows per batch, *fp16(1/(l+1)), +b_final.
__global__ __launch_bounds__(256, 2) void scan_kernel(
    const float4* __restrict__ g4, const float4* __restrict__ pp,
    const float* __restrict__ bfin, float4* __restrict__ out4) {
  __shared__ float4 sg[2][ROWS_PER_BLK];
  __shared__ float4 wq[2][4];
  __shared__ float4 boffs[2];

  const int tid = threadIdx.x;
  const int lane = tid & 63;
  const int wv = tid >> 6;
  const int bid = blockIdx.x;

  // Load this block's 128 g rows into LDS.
  if (tid < 2 * ROWS_PER_BLK) {
    const int bb = tid / ROWS_PER_BLK;
    const int i = tid - bb * ROWS_PER_BLK;
    sg[bb][i] = g4[(size_t)bb * L_TOTAL + bid * ROWS_PER_BLK + i];
  }

  // Offset: sum pp[j] for j < bid (both batches).
  float4 q0 = make_float4(0.f, 0.f, 0.f, 0.f);
  float4 q1 = make_float4(0.f, 0.f, 0.f, 0.f);
  for (int jj = tid; jj < bid; jj += 256) {
    q0 = f4add(q0, pp[jj]);
    q1 = f4add(q1, pp[NBLK + jj]);
  }
#pragma unroll
  for (int off = 32; off > 0; off >>= 1) {
    q0.x += __shfl_xor(q0.x, off); q0.y += __shfl_xor(q0.y, off);
    q0.z += __shfl_xor(q0.z, off); q0.w += __shfl_xor(q0.w, off);
    q1.x += __shfl_xor(q1.x, off); q1.y += __shfl_xor(q1.y, off);
    q1.z += __shfl_xor(q1.z, off); q1.w += __shfl_xor(q1.w, off);
  }
  if (lane == 0) { wq[0][wv] = q0; wq[1][wv] = q1; }
  __syncthreads();
  if (tid == 0) {
    boffs[0] = f4add(f4add(wq[0][0], wq[0][1]), f4add(wq[0][2], wq[0][3]));
    boffs[1] = f4add(f4add(wq[1][0], wq[1][1]), f4add(wq[1][2], wq[1][3]));
  }
  __syncthreads();

  // Hillis-Steele inclusive scan over the 64 rows per batch.
  const bool act = tid < 2 * ROWS_PER_BLK;
  const int bb = tid / ROWS_PER_BLK;       // 0 or 1 when act
  const int i = tid - bb * ROWS_PER_BLK;
#pragma unroll
  for (int d = 1; d < ROWS_PER_BLK; d <<= 1) {
    float4 addv = make_float4(0.f, 0.f, 0.f, 0.f);
    if (act && i >= d) addv = sg[bb][i - d];
    __syncthreads();
    if (act && i >= d) sg[bb][i] = f4add(sg[bb][i], addv);
    __syncthreads();
  }
  if (act) {
    const int l = bid * ROWS_PER_BLK + i;
    const float4 v = f4add(sg[bb][i], boffs[bb]);
    const float factor = fp16_roundtrip_pos(1.0f / (float)(l + 1));
    float4 o;
    o.x = fmaf(v.x, factor, bfin[0]);
    o.y = fmaf(v.y, factor, bfin[1]);
    o.z = fmaf(v.z, factor, bfin[2]);
    o.w = fmaf(v.w, factor, bfin[3]);
    out4[(size_t)bb * L_TOTAL + l] = o;
  }
}

extern "C" void kernel_launch(void* const* d_in, const int* in_sizes, int n_in,
                              void* d_out, int out_size, void* d_ws, size_t ws_size,
                              hipStream_t stream) {
  const int* ex = (const int*)d_in[0];            // example [2,128,128,3] int32
  const float4* win4 = (const float4*)d_in[1];    // W_in [1,1024]
  const float4* pos4 = (const float4*)d_in[2];    // pos_enc [49152,1024]
  const float4* wf4 = (const float4*)d_in[3];     // W_final [1024,4]
  const float* bfin = (const float*)d_in[4];      // b_final [4]
  float4* out4 = (float4*)d_out;

  float4* g4 = (float4*)d_ws;                     // [2*L_TOTAL] float4
  float4* pp = g4 + (size_t)2 * L_TOTAL;          // [2*NBLK] float4

  gpart_kernel<<<NBLK, 256, 0, stream>>>(ex, win4, pos4, wf4, g4, pp);
  scan_kernel<<<NBLK, 256, 0, stream>>>(g4, pp, bfin, out4);
}